// Round 13
// baseline (165.323 us; speedup 1.0000x reference)
//
#include <hip/hip_runtime.h>
#include <hip/hip_bf16.h>
#include <math.h>

// B=8, N=32, S=512, H=768, K=3, C=128, L=64, W=16
#define NEG_INF (-1e30f)

typedef _Float16 half8 __attribute__((ext_vector_type(8)));
typedef _Float16 half4 __attribute__((ext_vector_type(4)));
typedef float f32x4 __attribute__((ext_vector_type(4)));
typedef float f32x16 __attribute__((ext_vector_type(16)));

// ---------------------------------------------------------------------------
// Kernel 1 (prep): 2-plane split in MFMA FRAGMENT-MAJOR layout.
//   A2f[mt][kt][lane][8]: mt=m/32 (128), kt=k16-tile (96: plane0=0..47,
//     plane1=48..95), lane = (m&31) + 32*((k%16)>>3), 8 halfs k%8.
//     1 KB per (mt,kt) block -> wave fragment load = base + lane*16 (coalesced).
//   Btf[nt][kt][lane][8]: same for j-rows (36 nt-tiles).
//   Planes: p0 = hi = (f16)x, p1 = lo = (f16)((x-hi)*64); result combined
//   as aa + 2^-6*ab downstream (verified r8-r12, absmax 0.0).
//   fcT[i][c] fp32.
// ---------------------------------------------------------------------------
__global__ __launch_bounds__(256) void prep(
    const float* __restrict__ tokens, const float* __restrict__ span_w,
    const float* __restrict__ prefix_w, const float* __restrict__ suffix_w,
    const float* __restrict__ fc_w, _Float16* __restrict__ A2f,
    _Float16* __restrict__ Btf, float* __restrict__ fcT) {
  int bid = blockIdx.x;
  int t = threadIdx.x;
  if (bid < 3072) {  // A2f: 4 consecutive h per thread (one 8B store/plane)
    int g4 = (bid * 256 + t) * 4;
    int m = g4 / 768, h = g4 % 768;
    float4 x = *(const float4*)(tokens + g4);
    float xs[4] = {x.x, x.y, x.z, x.w};
    half4 hi, lo;
#pragma unroll
    for (int i = 0; i < 4; ++i) {
      _Float16 h_ = (_Float16)xs[i];
      hi[i] = h_;
      lo[i] = (_Float16)((xs[i] - (float)h_) * 64.0f);
    }
    const int mt = m >> 5;
    const int lane = (m & 31) + 32 * ((h >> 3) & 1);
    const int j0 = h & 7;  // 0 or 4
    const size_t base = ((size_t)mt * 96 + (h >> 4)) * 512 + lane * 8 + j0;
    *(half4*)(A2f + base) = hi;                 // plane0: kt = h>>4
    *(half4*)(A2f + base + (size_t)48 * 512) = lo;  // plane1: kt+48
  } else if (bid < 3216) {  // Btf: 8 h x 3 taps per thread (16B stores)
    int g = (bid - 3072) * 256 + t;  // over 3*128*96 = 36864
    int ws = g / 12288;
    int r = g % 12288;
    int c = r / 96, h = (r % 96) * 8;
    const float* wsrc = (ws == 0) ? prefix_w : (ws == 1) ? span_w : suffix_w;
    const float* src = wsrc + (size_t)(c * 768 + h) * 3;
    float wv[24];
#pragma unroll
    for (int i = 0; i < 6; ++i) *(float4*)&wv[i * 4] = *(const float4*)(src + i * 4);
#pragma unroll
    for (int tap = 0; tap < 3; ++tap) {
      half8 hi, lo;
#pragma unroll
      for (int i = 0; i < 8; ++i) {
        float x = wv[i * 3 + tap];
        _Float16 h_ = (_Float16)x;
        hi[i] = h_;
        lo[i] = (_Float16)((x - (float)h_) * 64.0f);
      }
      const int n = ws * 384 + tap * 128 + c;
      const int nt = n >> 5;
      const int lane = (n & 31) + 32 * ((h >> 3) & 1);
      const size_t base = ((size_t)nt * 96 + (h >> 4)) * 512 + lane * 8;
      *(half8*)(Btf + base) = hi;
      *(half8*)(Btf + base + (size_t)48 * 512) = lo;
    }
  } else {  // fcT
    int g = (bid - 3216) * 256 + t;
    int i = g >> 6, c = g & 63;
    fcT[g] = fc_w[c * 384 + i];
  }
}

// ---------------------------------------------------------------------------
// Kernel 2: ZERO-LDS MFMA GEMM with fragment-major operands.
//   Each wave's fragment load = one coalesced global_load_dwordx4 (1 KB/wave)
//   — fixes r11's strided-load failure while keeping its structure: no LDS
//   pipe (the ~20% MfmaUtil cap of r5-r12), no barriers, no staging.
//   Ct[j][m] = aa + 2^-6*ab; per k16: aa += A0*B0; ab += A1*B0 + A0*B1.
//   Block = 4 waves m-split (BM=128), BN=64; wave-tile 32x64 (2 n-subtiles).
//   All waves share B fragment addresses -> L1 hits. Grid (32,18)=576.
//   48 k16-iters, 6 loads + 6 MFMA each; loads pipeline under vmcnt.
// ---------------------------------------------------------------------------
__global__ __launch_bounds__(256) void gemm_f16(const _Float16* __restrict__ A2f,
                                                const _Float16* __restrict__ Btf,
                                                float* __restrict__ Ct) {
  const int w = threadIdx.x >> 6;
  const int lane = threadIdx.x & 63;
  const int mt = blockIdx.x * 4 + w;
  const int nt0 = blockIdx.y * 2;
  const _Float16* pa = A2f + (size_t)mt * 49152 + lane * 8;
  const _Float16* pb0 = Btf + (size_t)nt0 * 49152 + lane * 8;
  const _Float16* pb1 = pb0 + 49152;
  f32x16 aa0, ab0, aa1, ab1;
#pragma unroll
  for (int q = 0; q < 16; ++q) {
    aa0[q] = 0.f;
    ab0[q] = 0.f;
    aa1[q] = 0.f;
    ab1[q] = 0.f;
  }
#pragma unroll 2
  for (int kt = 0; kt < 48; ++kt) {
    const int o0 = kt * 512;
    const int o1 = o0 + 48 * 512;
    half8 a0 = *(const half8*)(pa + o0);
    half8 a1 = *(const half8*)(pa + o1);
    half8 b00 = *(const half8*)(pb0 + o0);
    half8 b01 = *(const half8*)(pb0 + o1);
    half8 b10 = *(const half8*)(pb1 + o0);
    half8 b11 = *(const half8*)(pb1 + o1);
    aa0 = __builtin_amdgcn_mfma_f32_32x32x16_f16(a0, b00, aa0, 0, 0, 0);
    aa1 = __builtin_amdgcn_mfma_f32_32x32x16_f16(a0, b10, aa1, 0, 0, 0);
    ab0 = __builtin_amdgcn_mfma_f32_32x32x16_f16(a1, b00, ab0, 0, 0, 0);
    ab1 = __builtin_amdgcn_mfma_f32_32x32x16_f16(a1, b10, ab1, 0, 0, 0);
    ab0 = __builtin_amdgcn_mfma_f32_32x32x16_f16(a0, b01, ab0, 0, 0, 0);
    ab1 = __builtin_amdgcn_mfma_f32_32x32x16_f16(a0, b11, ab1, 0, 0, 0);
  }
  // C/D layout (verified r9-r12): col(n)=lane&31, row(m)=(reg&3)+8*(reg>>2)+4*(lane>>5)
  const int l31 = lane & 31;
  const int hi32 = lane >> 5;
  const int m0 = mt * 32 + 4 * hi32;
  {
    const int n_out = nt0 * 32 + l31;
    float* cp = Ct + (size_t)n_out * 4096 + m0;
#pragma unroll
    for (int r = 0; r < 4; ++r) {
      f32x4 v;
#pragma unroll
      for (int q = 0; q < 4; ++q) v[q] = aa0[4 * r + q] + 0.015625f * ab0[4 * r + q];
      *(f32x4*)(cp + 8 * r) = v;
    }
  }
  {
    const int n_out = (nt0 + 1) * 32 + l31;
    float* cp = Ct + (size_t)n_out * 4096 + m0;
#pragma unroll
    for (int r = 0; r < 4; ++r) {
      f32x4 v;
#pragma unroll
      for (int q = 0; q < 4; ++q) v[q] = aa1[4 * r + q] + 0.015625f * ab1[4 * r + q];
      *(f32x4*)(cp + 8 * r) = v;
    }
  }
}

// ---------------------------------------------------------------------------
// Kernel 3: per-(b,c) tap-combine + prefix-max / suffix-max scans
// ---------------------------------------------------------------------------
__global__ __launch_bounds__(256) void scan_kernel(const float* __restrict__ Ct,
                                                   const int* __restrict__ wsl,
                                                   float* __restrict__ PM2,
                                                   float* __restrict__ SM2) {
  int pair = blockIdx.x * 4 + (threadIdx.x >> 6);
  int b = pair >> 7;
  int c = pair & 127;
  int lane = threadIdx.x & 63;
  int mb = b * 512;
  int t0 = lane * 8;
  const float* p0 = Ct + (size_t)(0 + c) * 4096 + mb;
  const float* p1 = Ct + (size_t)(128 + c) * 4096 + mb;
  const float* p2 = Ct + (size_t)(256 + c) * 4096 + mb;
  float v[8];
#pragma unroll
  for (int i = 0; i < 8; i++) {
    int t = t0 + i;
    v[i] = (t < 494) ? (p0[t] + p1[t + 1] + p2[t + 2]) : NEG_INF;
  }
#pragma unroll
  for (int i = 1; i < 8; i++) v[i] = fmaxf(v[i], v[i - 1]);
  float x = v[7];
#pragma unroll
  for (int d = 1; d < 64; d <<= 1) {
    float y = __shfl_up(x, d);
    if (lane >= d) x = fmaxf(x, y);
  }
  float excl = __shfl_up(x, 1);
  if (lane == 0) excl = NEG_INF;
  float* pm = PM2 + (size_t)pair * 512;
#pragma unroll
  for (int i = 0; i < 8; i++) {
    int t = t0 + i;
    if (t < 494) pm[t] = fmaxf(v[i], excl);
  }
  const float* s0 = Ct + (size_t)(768 + c) * 4096 + mb;
  const float* s1 = Ct + (size_t)(896 + c) * 4096 + mb;
  const float* s2 = Ct + (size_t)(1024 + c) * 4096 + mb;
  int qmax = wsl[b] - 3;
  if (qmax > 509) qmax = 509;
  float u[8];
#pragma unroll
  for (int i = 0; i < 8; i++) {
    int q = t0 + i;
    u[i] = (q <= qmax) ? (s0[q] + s1[q + 1] + s2[q + 2]) : NEG_INF;
  }
#pragma unroll
  for (int i = 6; i >= 0; i--) u[i] = fmaxf(u[i], u[i + 1]);
  float xr = u[0];
#pragma unroll
  for (int d = 1; d < 64; d <<= 1) {
    float y = __shfl_down(xr, d);
    if (lane < 64 - d) xr = fmaxf(xr, y);
  }
  float exclr = __shfl_down(xr, 1);
  if (lane == 63) exclr = NEG_INF;
  float* sm = SM2 + (size_t)pair * 512;
#pragma unroll
  for (int i = 0; i < 8; i++) sm[t0 + i] = fmaxf(u[i], exclr);
}

// ---------------------------------------------------------------------------
// Kernel 4: per-span features + coalesced FC + sigmoid + threshold
// ---------------------------------------------------------------------------
__global__ __launch_bounds__(128) void span_kernel(
    const float* __restrict__ Ct, const float* __restrict__ PM2,
    const float* __restrict__ SM2, const float* __restrict__ prefix_b,
    const float* __restrict__ span_b, const float* __restrict__ suffix_b,
    const float* __restrict__ fcT, const float* __restrict__ fc_b,
    const int* __restrict__ spans, const int* __restrict__ wsl,
    float* __restrict__ out) {
  __shared__ float sfeat[384];
  __shared__ float part[64];
  int sp = blockIdx.x;
  int b = sp >> 5;
  int c = threadIdx.x;
  int s = spans[sp * 2], e = spans[sp * 2 + 1];
  int Lb = wsl[b];
  int mb = b * 512;
  {  // prefix (T=496)
    const float* t0p = Ct + (size_t)c * 4096 + mb;
    const float* t1p = Ct + (size_t)(128 + c) * 4096 + mb;
    float m = NEG_INF;
    if (s >= 3) m = fmaxf(m, PM2[(size_t)(b * 128 + c) * 512 + s - 3]);
    if (s >= 2 && s <= 495) m = fmaxf(m, t0p[s - 2] + t1p[s - 1]);
    if (s >= 1 && s <= 494) m = fmaxf(m, t0p[s - 1]);
    if (s <= 493) m = fmaxf(m, 0.0f);
    sfeat[c] = m + prefix_b[c];
  }
  {  // span (T=16)
    const float* u0 = Ct + (size_t)(384 + c) * 4096 + mb;
    const float* u1 = Ct + (size_t)(512 + c) * 4096 + mb;
    const float* u2 = Ct + (size_t)(640 + c) * 4096 + mb;
    int w = e - s;
    float m = NEG_INF;
    for (int p = 0; p + 2 < w; ++p)
      m = fmaxf(m, u0[s + p] + u1[s + p + 1] + u2[s + p + 2]);
    if (w >= 2 && w <= 15) m = fmaxf(m, u0[s + w - 2] + u1[s + w - 1]);
    if (w <= 14) m = fmaxf(m, u0[s + w - 1]);
    if (w <= 13) m = fmaxf(m, 0.0f);
    sfeat[128 + c] = m + span_b[c];
  }
  {  // suffix (T=511)
    const float* x0 = Ct + (size_t)(768 + c) * 4096 + mb;
    const float* x1 = Ct + (size_t)(896 + c) * 4096 + mb;
    float m = NEG_INF;
    if (e <= Lb - 3) m = fmaxf(m, SM2[(size_t)(b * 128 + c) * 512 + e]);
    if (Lb - 2 - e >= 0 && Lb - 2 - e <= 508)
      m = fmaxf(m, x0[Lb - 2] + x1[Lb - 1]);
    if (Lb - 1 - e >= 0 && Lb - 1 - e <= 508) m = fmaxf(m, x0[Lb - 1]);
    if (Lb - e <= 508) m = fmaxf(m, 0.0f);
    sfeat[256 + c] = m + suffix_b[c];
  }
  __syncthreads();
  {
    int cc = threadIdx.x & 63;
    int half = threadIdx.x >> 6;
    float acc2 = 0.0f;
    const float* fp = fcT + (size_t)(half * 192) * 64 + cc;
    const float* sf = sfeat + half * 192;
#pragma unroll 8
    for (int i = 0; i < 192; ++i) acc2 = fmaf(sf[i], fp[(size_t)i * 64], acc2);
    if (half) part[cc] = acc2;
    __syncthreads();
    if (!half) {
      float a = acc2 + part[cc] + fc_b[cc];
      float pr = 1.0f / (1.0f + expf(-a));
      out[sp * 64 + cc] = pr;
      out[16384 + sp * 64 + cc] = (pr > 0.5f) ? 1.0f : 0.0f;
    }
  }
}

// ---------------------------------------------------------------------------
extern "C" void kernel_launch(void* const* d_in, const int* in_sizes, int n_in,
                              void* d_out, int out_size, void* d_ws,
                              size_t ws_size, hipStream_t stream) {
  const float* tokens = (const float*)d_in[0];
  const float* span_w = (const float*)d_in[1];
  const float* span_b = (const float*)d_in[2];
  const float* prefix_w = (const float*)d_in[3];
  const float* prefix_b = (const float*)d_in[4];
  const float* suffix_w = (const float*)d_in[5];
  const float* suffix_b = (const float*)d_in[6];
  const float* fc_w = (const float*)d_in[7];
  const float* fc_b = (const float*)d_in[8];
  const int* spans = (const int*)d_in[9];
  const int* wsl = (const int*)d_in[10];
  float* out = (float*)d_out;

  char* ws = (char*)d_ws;
  float* Ct = (float*)ws;                      // 1152*4096*4 = 18874368
  _Float16* A2f = (_Float16*)(ws + 18874368);  // 128*96*512*2 = 12582912
  _Float16* Btf = (_Float16*)(ws + 31457280);  // 36*96*512*2  =  3538944
  float* PM2 = (float*)(ws + 34996224);        // 2097152
  float* SM2 = (float*)(ws + 37093376);        // 2097152
  float* fcT = (float*)(ws + 39190528);        // 98304

  hipLaunchKernelGGL(prep, dim3(3312), dim3(256), 0, stream, tokens, span_w,
                     prefix_w, suffix_w, fc_w, A2f, Btf, fcT);
  hipLaunchKernelGGL(gemm_f16, dim3(32, 18), dim3(256), 0, stream, A2f, Btf, Ct);
  hipLaunchKernelGGL(scan_kernel, dim3(256), dim3(256), 0, stream, Ct, wsl,
                     PM2, SM2);
  hipLaunchKernelGGL(span_kernel, dim3(256), dim3(128), 0, stream, Ct, PM2,
                     SM2, prefix_b, span_b, suffix_b, fcT, fc_b, spans, wsl,
                     out);
}